// Round 2
// baseline (315.277 us; speedup 1.0000x reference)
//
#include <hip/hip_runtime.h>

// CircuitModel: sequential Oja/Hebbian plasticity scan.
//   y_t = sigmoid(w_t.x_t); w_{t+1} = b_t*w_t + a_t*x_t,
//   a_t = lr*th0*y_t, b_t = 1 + lr*th1*y_t^2; out[t,p] = y_t at observed rows.
//
// R1-R17: see journal. R15 best = 191.6us scan / 248 total. Structure:
//   D=8 block linearization, Gram band kernel + register-pipelined scan,
//   1 wave per observed row = 256 waves = 64 CUs -> 75% of chip idle.
// R18: re-baseline after container failure: 192.0us scan confirmed.
// R19: 4-way N_IN split. 4 waves/row share one WG (256 WGs, 1/CU,
//   1024 waves = every SIMD on chip). Each wave owns a 128-float slice:
//   dot partials 64->16 slots, w-update 72->18, stage 16->8 loads.
//   Cross-wave reduce of the 8 boundary dots once per block via 256B LDS
//   (double-buffered, ONE raw s_barrier per block; manual lgkmcnt only —
//   __syncthreads would vmcnt(0)-drain the x prefetch pipeline).
//   Scalar loop (sigmoid + band q-prop) stays wave-redundant (uniform).
//   All 4 waves issue the identical y-store to keep vmcnt uniform for WAIT1.

constexpr int N_IN    = 512;
constexpr int T       = 2048;
constexpr int N_OBS   = 256;
constexpr int D       = 8;            // linearization block size
constexpr int NBLK    = T / D;        // 256
constexpr int BANDPAD = 64;           // packed-band floats per block (28 used)
constexpr float LOG2E = 1.44269504088896f;

typedef float f4 __attribute__((ext_vector_type(4)));
typedef float f2 __attribute__((ext_vector_type(2)));

// Packed band layout for block b (t0=8b): entry k = x_{t0+i}.x_{t0+i+j},
// k = BOFF[i] + (j-1), i=0..6, j=1..7-i (28 entries).
__device__ constexpr int BOFF[8] = {0, 7, 13, 18, 22, 25, 27, 28};

// DPP add-reduce step via builtin (old=0 additive identity; compiler handles
// the VALU->DPP hazard slots — R14 lesson).
#define DPP_ADD(v, ctrl, rmask)                                                \
    v += __int_as_float(__builtin_amdgcn_update_dpp(                           \
        0, __float_as_int(v), (ctrl), (rmask), 0xf, false))

__device__ __forceinline__ float wave64_sum_bcast(float v) {
    DPP_ADD(v, 0x111, 0xf); // row_shr:1
    DPP_ADD(v, 0x112, 0xf); // row_shr:2
    DPP_ADD(v, 0x114, 0xf); // row_shr:4
    DPP_ADD(v, 0x118, 0xf); // row_shr:8
    DPP_ADD(v, 0x142, 0xa); // row_bcast:15
    DPP_ADD(v, 0x143, 0xc); // row_bcast:31 -> lane63 = total
    return __int_as_float(__builtin_amdgcn_readlane(__float_as_int(v), 63));
}

// Serial-fma lane-partial dot over 8 elements (gram kernel).
__device__ __forceinline__ float dot8s(const f4& w0, const f4& w1,
                                       const f4& x0, const f4& x1) {
    float p = w0.x * x0.x;
    p = fmaf(w0.y, x0.y, p);
    p = fmaf(w0.z, x0.z, p);
    p = fmaf(w0.w, x0.w, p);
    p = fmaf(w1.x, x1.x, p);
    p = fmaf(w1.y, x1.y, p);
    p = fmaf(w1.z, x1.z, p);
    p = fmaf(w1.w, x1.w, p);
    return p;
}

// ---- explicit-VMEM primitives ---------------------------------------------
#define GLOADX2(dst, addr, offstr)                                             \
    asm volatile("global_load_dwordx2 %0, %1, off offset:" offstr              \
                 : "=v"(dst) : "v"(addr))

// Stage one block's 8 x-row slices (128 floats each): 8 vmem load issues.
__device__ __forceinline__ void stage8(f2 (&xb)[8], const char* xa) {
    const char* a0 = xa;
    const char* a1 = xa + 4096;
    const char* a2 = xa + 8192;
    const char* a3 = xa + 12288;
    GLOADX2(xb[0], a0, "0");  GLOADX2(xb[1], a0, "2048");
    GLOADX2(xb[2], a1, "0");  GLOADX2(xb[3], a1, "2048");
    GLOADX2(xb[4], a2, "0");  GLOADX2(xb[5], a2, "2048");
    GLOADX2(xb[6], a3, "0");  GLOADX2(xb[7], a3, "2048");
}

#define TIEBUF8(ins, buf)                                                      \
    asm volatile(ins                                                           \
        : "+v"(buf[0]), "+v"(buf[1]), "+v"(buf[2]), "+v"(buf[3]),              \
          "+v"(buf[4]), "+v"(buf[5]), "+v"(buf[6]), "+v"(buf[7]))

// Pin: consumers of buf must schedule after this point (dataflow), and this
// point is after the preceding volatile loads (volatile order). Zero insts.
#define PIN(buf)      TIEBUF8("", buf)
// Wait: drain all but the newest N outstanding vmem ops, tying buf's values.
#define WAIT1(buf)    TIEBUF8("s_waitcnt vmcnt(1)", buf)
#define WAIT0(buf)    TIEBUF8("s_waitcnt vmcnt(0)", buf)

// ---- Kernel 1: packed Gram band, one wave per 8-step block -----------------
__global__ __launch_bounds__(64) void gram_kernel(const float* __restrict__ X,
                                                  float* __restrict__ P) {
    const int b    = blockIdx.x;          // 0..NBLK-1
    const int lane = threadIdx.x;         // 0..63
    const int t0   = b * D;
    const f4* Xv = (const f4*)(X + (long)t0 * N_IN);
    f4 r[8][2];
    #pragma unroll
    for (int i = 0; i < 8; ++i) {
        r[i][0] = Xv[i * (N_IN / 4) + lane * 2 + 0];
        r[i][1] = Xv[i * (N_IN / 4) + lane * 2 + 1];
    }
    float s[28];
    #pragma unroll
    for (int i = 0; i < 7; ++i) {
        #pragma unroll
        for (int j = 1; j <= 7 - i; ++j) {
            s[BOFF[i] + j - 1] =
                wave64_sum_bcast(dot8s(r[i][0], r[i][1], r[i + j][0], r[i + j][1]));
        }
    }
    if (lane == 0) {
        #pragma unroll
        for (int k = 0; k < 28; ++k) P[b * BANDPAD + k] = s[k];
    }
}

// ---- process one block from a register buffer ------------------------------
// All z/q/w quantities are in log2e-scaled space (w~ = log2e*w); y itself is
// exact sigmoid, via y = rcp(1 + 2^(-z~)).
__device__ __forceinline__ void process_block(
    const f2 (&xb)[8], const float (&bs)[28], int t0, int lane, int wid,
    int col, int buf, float* __restrict__ smem,
    f2& w, float th0s, float th1, float* __restrict__ out)
{
    // Boundary: partial q~_d = w~_slice . x_slice_{t0+d} (8 indep chains).
    float qp[D];
    #pragma unroll
    for (int d = 0; d < D; ++d) {
        float p = w.x * xb[d].x;
        p = fmaf(w.y, xb[d].y, p);
        qp[d] = wave64_sum_bcast(p);
    }

    // Pack lane-indexed (lane d holds qp[d]) and cross-wave reduce via LDS.
    // Layout: smem[buf*32 + d*4 + wid], double-buffered, 256 B total.
    float packv = qp[0];
    #pragma unroll
    for (int d = 1; d < D; ++d) packv = (lane == d) ? qp[d] : packv;
    if (lane < D) smem[buf * 32 + lane * 4 + wid] = packv;
    asm volatile("s_waitcnt lgkmcnt(0)" ::: "memory");
    __builtin_amdgcn_s_barrier();
    asm volatile("" ::: "memory");
    const f4 qq = *reinterpret_cast<const f4*>(&smem[buf * 32 + (lane & 7) * 4]);
    const float qsum = (qq.x + qq.y) + (qq.z + qq.w);  // lane l: total q[l&7]
    float q[D];
    #pragma unroll
    for (int d = 0; d < D; ++d)
        q[d] = __int_as_float(
            __builtin_amdgcn_readlane(__float_as_int(qsum), d));

    // Eight steps: sigmoid + q~ propagation (wave-uniform, redundant across
    // the 4 waves — same wall time, different SIMDs). w~-update deferred.
    float av[D], bv[D];
    float ys = 0.0f;
    float z = q[0];
    #pragma unroll
    for (int i = 0; i < D; ++i) {
        const float y =
            __builtin_amdgcn_rcpf(1.0f + __builtin_amdgcn_exp2f(-z));
        if (lane == i) ys = y;

        const float a = th0s * y;              // a~ = log2e * lr*th0 * y
        const float b = fmaf(th1 * y, y, 1.0f);
        av[i] = a;
        bv[i] = b;

        #pragma unroll
        for (int d = i + 1; d < D; ++d)
            q[d] = fmaf(b, q[d], a * bs[BOFF[i] + (d - i) - 1]);
        if (i < D - 1) z = q[i + 1];
    }

    // Batched w~-update on this wave's 2-float slice:
    // w' = B*w + sum_i c_i x_i, c_i = a~_i * prod_{j>i} b_j.
    float c[D];
    float sfx = 1.0f;
    #pragma unroll
    for (int i = D - 1; i >= 0; --i) {
        c[i] = av[i] * sfx;
        sfx *= bv[i];
    }
    const float B = sfx;

    f2 acc;
    acc.x = c[0] * xb[0].x;
    acc.y = c[0] * xb[0].y;
    #pragma unroll
    for (int i = 1; i < D; ++i) {
        acc.x = fmaf(c[i], xb[i].x, acc.x);
        acc.y = fmaf(c[i], xb[i].y, acc.y);
    }
    w.x = fmaf(B, w.x, acc.x);
    w.y = fmaf(B, w.y, acc.y);

    // Batched store: lanes 0..7 write y_0..y_7 (exec-masked). All 4 waves
    // issue it (same addr, same data) so vmcnt is wave-uniform for WAIT1.
    float* oaddr = out + (size_t)(t0 + lane) * N_OBS + col;
    asm volatile("s_mov_b64 vcc, exec\n\t"
                 "s_mov_b64 exec, 0xff\n\t"
                 "global_store_dword %0, %1, off\n\t"
                 "s_mov_b64 exec, vcc"
                 :: "v"(oaddr), "v"(ys) : "vcc");
}

__device__ __forceinline__ void load_band(float (&bs)[28], const float* pb) {
    #pragma unroll
    for (int k = 0; k < 28; ++k) bs[k] = pb[k];   // wave-uniform -> s_load
}

// ---- Kernel 2: the scan ----------------------------------------------------
// One WG (4 waves) per observed row; wave wid owns N_IN slice
// [wid*128, wid*128+128), 2 floats per lane.
__global__ __launch_bounds__(256, 1) void oja_scan_kernel(
    const float* __restrict__ X,     // [T, N_IN]
    const float* __restrict__ Winit, // [N_OUT, N_IN]
    const float* __restrict__ theta, // [2]
    const int*   __restrict__ obs,   // [N_OBS]
    const float* __restrict__ P,     // [NBLK, BANDPAD] packed band (d_ws)
    float*       __restrict__ out)   // [T, N_OBS]
{
    __shared__ __align__(16) float smem[64];  // 2 bufs x 8 dots x 4 waves

    const int tid  = threadIdx.x;
    const int wid  = tid >> 6;            // 0..3 (1 wave per SIMD)
    const int lane = tid & 63;
    const int col  = blockIdx.x;          // observed-row index 0..255

    const int row = obs[col];
    const float lr   = 1.0f / (float)N_IN;
    const float th0s = theta[0] * lr * LOG2E;  // log2e-space a coefficient
    const float th1  = theta[1] * lr;

    // Weights held in log2e space: w~ = log2e * w. This wave's slice.
    const f2* Wv = (const f2*)(Winit + (long)row * N_IN + wid * 128);
    f2 w = Wv[lane];
    w.x *= LOG2E; w.y *= LOG2E;

    const char* xbase =
        (const char*)X + (size_t)(wid * 128 + lane * 2) * 4;

    f2 xA[8], xB[8];
    float bsA[28], bsB[28];

    // Prologue: block 0 into A, full drain.
    stage8(xA, xbase);
    load_band(bsA, P);
    WAIT0(xA);

    for (int blk = 0; blk < NBLK; blk += 2) {
        // Half 1: stage blk+1 into B; PIN(A) forces process(A)'s compute
        // after the loads; WAIT1 drains B's 8 loads (issued ~1 block ago),
        // leaving only the newest out-store in flight.
        const int b1 = (blk + 1 < NBLK) ? (blk + 1) : (NBLK - 1);
        stage8(xB, xbase + (size_t)b1 * 16384);
        load_band(bsB, P + (size_t)b1 * BANDPAD);
        PIN(xA);
        process_block(xA, bsA, blk * D, lane, wid, col, 0, smem,
                      w, th0s, th1, out);
        WAIT1(xB);

        // Half 2: symmetric.
        const int b2 = (blk + 2 < NBLK) ? (blk + 2) : (NBLK - 1);
        stage8(xA, xbase + (size_t)b2 * 16384);
        load_band(bsA, P + (size_t)b2 * BANDPAD);
        PIN(xB);
        process_block(xB, bsB, (blk + 1) * D, lane, wid, col, 1, smem,
                      w, th0s, th1, out);
        WAIT1(xA);
    }
}

extern "C" void kernel_launch(void* const* d_in, const int* in_sizes, int n_in,
                              void* d_out, int out_size, void* d_ws, size_t ws_size,
                              hipStream_t stream) {
    const float* X     = (const float*)d_in[0];
    const float* Winit = (const float*)d_in[1];
    const float* theta = (const float*)d_in[2];
    const int*   obs   = (const int*)d_in[3];
    float*       out   = (float*)d_out;
    float*       P     = (float*)d_ws;   // NBLK*BANDPAD floats = 64 KB

    // Gram band: one wave per block.
    gram_kernel<<<NBLK, 64, 0, stream>>>(X, P);

    // Scan: 256 WGs x 4 waves = 1024 waves — every SIMD on the chip.
    oja_scan_kernel<<<256, 256, 0, stream>>>(X, Winit, theta, obs, P, out);
}